// Round 1
// baseline (95.628 us; speedup 1.0000x reference)
//
#include <hip/hip_runtime.h>

// GlobalAttention: out = softmax_j(scores) @ H
// scores[i,j] = sum_m lrelu(Wh1[i,m]+Wh2[j,m]) * a[m]
// Using lrelu(t) = 0.6 t + 0.4|t|, and dropping the row-constant part in softmax:
// scores'[i,j] = s2[j] + sum_m b[m]*|Wh1[i,m]+Wh2[j,m]|,  b[m]=0.4*a[m],
// s2[j] = 0.6 * sum_m a[m]*Wh2[j,m].

#define N_ROWS 1024
#define D_DIM  256

// ---------- K1: Wh[n][m] = sum_k H[n][k] * Wre[m][k]  (n<1024, m<512, k<256)
// Wre[m][k] = W[m&255][(m>>8)*256 + k]
__global__ __launch_bounds__(256) void k1_gemm_wh(const float* __restrict__ H,
                                                  const float* __restrict__ W,
                                                  float* __restrict__ Wh) {
    __shared__ float As[64][68];
    __shared__ float Bs[64][68];
    const int bi = blockIdx.x, bj = blockIdx.y;
    const int t = threadIdx.x;
    const int ti = t >> 4, tj = t & 15;
    const int i0 = ti * 4, j0 = tj * 4;
    const int half = bj >> 2;
    float acc[4][4] = {};
    for (int kc = 0; kc < 256; kc += 64) {
#pragma unroll
        for (int rr = 0; rr < 4; ++rr) {
            const int row = ti + rr * 16;
            const int col = tj * 4;
            *(float4*)&As[row][col] =
                *(const float4*)&H[(bi * 64 + row) * 256 + kc + col];
            const int wrow = (bj * 64 + row) & 255;
            *(float4*)&Bs[row][col] =
                *(const float4*)&W[wrow * 512 + half * 256 + kc + col];
        }
        __syncthreads();
#pragma unroll
        for (int k = 0; k < 64; k += 4) {
            float4 a[4], b[4];
#pragma unroll
            for (int r = 0; r < 4; ++r) a[r] = *(const float4*)&As[i0 + r][k];
#pragma unroll
            for (int c = 0; c < 4; ++c) b[c] = *(const float4*)&Bs[j0 + c][k];
#pragma unroll
            for (int r = 0; r < 4; ++r)
#pragma unroll
                for (int c = 0; c < 4; ++c) {
                    acc[r][c] = fmaf(a[r].x, b[c].x, acc[r][c]);
                    acc[r][c] = fmaf(a[r].y, b[c].y, acc[r][c]);
                    acc[r][c] = fmaf(a[r].z, b[c].z, acc[r][c]);
                    acc[r][c] = fmaf(a[r].w, b[c].w, acc[r][c]);
                }
        }
        __syncthreads();
    }
#pragma unroll
    for (int r = 0; r < 4; ++r) {
        float4 v = make_float4(acc[r][0], acc[r][1], acc[r][2], acc[r][3]);
        *(float4*)&Wh[(bi * 64 + i0 + r) * 512 + bj * 64 + j0] = v;
    }
}

// ---------- K1b: s2[j] = 0.6 * sum_m a[m] * Wh2[j][m]   (one wave per row)
__global__ __launch_bounds__(256) void k1b_s2(const float* __restrict__ Wh,
                                              const float* __restrict__ a,
                                              float* __restrict__ s2) {
    const int t = threadIdx.x;
    const int lane = t & 63, w = t >> 6;
    const int row = blockIdx.x * 4 + w;
    float4 x = *(const float4*)&Wh[row * 512 + 256 + lane * 4];
    float4 av = *(const float4*)&a[lane * 4];
    float d = x.x * av.x + x.y * av.y + x.z * av.z + x.w * av.w;
#pragma unroll
    for (int off = 32; off > 0; off >>= 1) d += __shfl_xor(d, off);
    if (lane == 0) s2[row] = 0.6f * d;
}

// ---------- K2: scores'[i][j] = s2[j] + sum_m b[m]*|Wh1[i][m]+Wh2[j][m]|
__global__ __launch_bounds__(256) void k2_scores(const float* __restrict__ Wh,
                                                 const float* __restrict__ a,
                                                 const float* __restrict__ s2,
                                                 float* __restrict__ scores) {
    __shared__ float X1[64][68];
    __shared__ float X2[64][68];
    __shared__ float bsh[256];
    const int bi = blockIdx.x, bj = blockIdx.y;
    const int t = threadIdx.x;
    const int ti = t >> 4, tj = t & 15;
    const int i0 = ti * 4, j0 = tj * 4;
    if (t < 64) {
        float4 av = *(const float4*)&a[t * 4];
        *(float4*)&bsh[t * 4] =
            make_float4(0.4f * av.x, 0.4f * av.y, 0.4f * av.z, 0.4f * av.w);
    }
    float acc[4][4] = {};
    for (int mc = 0; mc < 256; mc += 64) {
#pragma unroll
        for (int rr = 0; rr < 4; ++rr) {
            const int row = ti + rr * 16;
            const int col = tj * 4;
            *(float4*)&X1[row][col] =
                *(const float4*)&Wh[(bi * 64 + row) * 512 + mc + col];
            *(float4*)&X2[row][col] =
                *(const float4*)&Wh[(bj * 64 + row) * 512 + 256 + mc + col];
        }
        __syncthreads();
#pragma unroll
        for (int k = 0; k < 64; k += 4) {
            float4 x1[4], x2[4];
#pragma unroll
            for (int r = 0; r < 4; ++r) x1[r] = *(const float4*)&X1[i0 + r][k];
#pragma unroll
            for (int c = 0; c < 4; ++c) x2[c] = *(const float4*)&X2[j0 + c][k];
            const float4 bv = *(const float4*)&bsh[mc + k];
#pragma unroll
            for (int r = 0; r < 4; ++r)
#pragma unroll
                for (int c = 0; c < 4; ++c) {
                    acc[r][c] = fmaf(fabsf(x1[r].x + x2[c].x), bv.x, acc[r][c]);
                    acc[r][c] = fmaf(fabsf(x1[r].y + x2[c].y), bv.y, acc[r][c]);
                    acc[r][c] = fmaf(fabsf(x1[r].z + x2[c].z), bv.z, acc[r][c]);
                    acc[r][c] = fmaf(fabsf(x1[r].w + x2[c].w), bv.w, acc[r][c]);
                }
        }
        __syncthreads();
    }
    const float4 sv = *(const float4*)&s2[bj * 64 + j0];
#pragma unroll
    for (int r = 0; r < 4; ++r) {
        float4 v = make_float4(acc[r][0] + sv.x, acc[r][1] + sv.y,
                               acc[r][2] + sv.z, acc[r][3] + sv.w);
        *(float4*)&scores[(bi * 64 + i0 + r) * 1024 + bj * 64 + j0] = v;
    }
}

// ---------- K3: row softmax in-place (one block per row)
__global__ __launch_bounds__(256) void k3_softmax(float* __restrict__ scores) {
    const int i = blockIdx.x, t = threadIdx.x;
    __shared__ float red[8];
    float4 v = *(float4*)&scores[i * 1024 + t * 4];
    float m = fmaxf(fmaxf(v.x, v.y), fmaxf(v.z, v.w));
#pragma unroll
    for (int off = 32; off > 0; off >>= 1) m = fmaxf(m, __shfl_xor(m, off));
    const int w = t >> 6;
    if ((t & 63) == 0) red[w] = m;
    __syncthreads();
    const float M = fmaxf(fmaxf(red[0], red[1]), fmaxf(red[2], red[3]));
    float4 e;
    e.x = __expf(v.x - M);
    e.y = __expf(v.y - M);
    e.z = __expf(v.z - M);
    e.w = __expf(v.w - M);
    float s = e.x + e.y + e.z + e.w;
#pragma unroll
    for (int off = 32; off > 0; off >>= 1) s += __shfl_xor(s, off);
    if ((t & 63) == 0) red[4 + w] = s;
    __syncthreads();
    const float rs = 1.0f / (red[4] + red[5] + red[6] + red[7]);
    e.x *= rs; e.y *= rs; e.z *= rs; e.w *= rs;
    *(float4*)&scores[i * 1024 + t * 4] = e;
}

// ---------- K4: part[s][i][c] = sum_{j in split s} alpha[i][j]*H[j][c]
__global__ __launch_bounds__(256) void k4_av(const float* __restrict__ alpha,
                                             const float* __restrict__ H,
                                             float* __restrict__ part) {
    __shared__ float As[64][68];
    __shared__ float Hs[64][68];
    const int bi = blockIdx.x;  // i-tile 0..15
    const int bc = blockIdx.y;  // c-tile 0..3
    const int s = blockIdx.z;   // j-split 0..3
    const int t = threadIdx.x;
    const int ti = t >> 4, tj = t & 15;
    const int i0 = ti * 4, c0 = tj * 4;
    float acc[4][4] = {};
    for (int jc = s * 256; jc < s * 256 + 256; jc += 64) {
#pragma unroll
        for (int rr = 0; rr < 4; ++rr) {
            const int row = ti + rr * 16;
            const int col = tj * 4;
            *(float4*)&As[row][col] =
                *(const float4*)&alpha[(bi * 64 + row) * 1024 + jc + col];
            *(float4*)&Hs[row][col] =
                *(const float4*)&H[(jc + row) * 256 + bc * 64 + col];
        }
        __syncthreads();
#pragma unroll
        for (int k = 0; k < 64; k += 4) {
            float4 av[4], h[4];
#pragma unroll
            for (int r = 0; r < 4; ++r) av[r] = *(const float4*)&As[i0 + r][k];
#pragma unroll
            for (int q = 0; q < 4; ++q) h[q] = *(const float4*)&Hs[k + q][c0];
#pragma unroll
            for (int r = 0; r < 4; ++r) {
                float aq;
                aq = av[r].x;
                acc[r][0] = fmaf(aq, h[0].x, acc[r][0]);
                acc[r][1] = fmaf(aq, h[0].y, acc[r][1]);
                acc[r][2] = fmaf(aq, h[0].z, acc[r][2]);
                acc[r][3] = fmaf(aq, h[0].w, acc[r][3]);
                aq = av[r].y;
                acc[r][0] = fmaf(aq, h[1].x, acc[r][0]);
                acc[r][1] = fmaf(aq, h[1].y, acc[r][1]);
                acc[r][2] = fmaf(aq, h[1].z, acc[r][2]);
                acc[r][3] = fmaf(aq, h[1].w, acc[r][3]);
                aq = av[r].z;
                acc[r][0] = fmaf(aq, h[2].x, acc[r][0]);
                acc[r][1] = fmaf(aq, h[2].y, acc[r][1]);
                acc[r][2] = fmaf(aq, h[2].z, acc[r][2]);
                acc[r][3] = fmaf(aq, h[2].w, acc[r][3]);
                aq = av[r].w;
                acc[r][0] = fmaf(aq, h[3].x, acc[r][0]);
                acc[r][1] = fmaf(aq, h[3].y, acc[r][1]);
                acc[r][2] = fmaf(aq, h[3].z, acc[r][2]);
                acc[r][3] = fmaf(aq, h[3].w, acc[r][3]);
            }
        }
        __syncthreads();
    }
#pragma unroll
    for (int r = 0; r < 4; ++r) {
        float4 v = make_float4(acc[r][0], acc[r][1], acc[r][2], acc[r][3]);
        *(float4*)&part[s * 262144 + (bi * 64 + i0 + r) * 256 + bc * 64 + c0] = v;
    }
}

// ---------- K5: out = sum of 4 partials
__global__ __launch_bounds__(256) void k5_reduce(const float* __restrict__ part,
                                                 float* __restrict__ out) {
    const int idx = (blockIdx.x * 256 + threadIdx.x) * 4;
    float4 p0 = *(const float4*)&part[idx];
    float4 p1 = *(const float4*)&part[262144 + idx];
    float4 p2 = *(const float4*)&part[524288 + idx];
    float4 p3 = *(const float4*)&part[786432 + idx];
    float4 o = make_float4(p0.x + p1.x + p2.x + p3.x, p0.y + p1.y + p2.y + p3.y,
                           p0.z + p1.z + p2.z + p3.z, p0.w + p1.w + p2.w + p3.w);
    *(float4*)&out[idx] = o;
}

extern "C" void kernel_launch(void* const* d_in, const int* in_sizes, int n_in,
                              void* d_out, int out_size, void* d_ws, size_t ws_size,
                              hipStream_t stream) {
    const float* H = (const float*)d_in[0];
    const float* W = (const float*)d_in[1];
    const float* a = (const float*)d_in[2];
    float* out = (float*)d_out;
    float* ws = (float*)d_ws;

    float* scores = ws;                          // 1M floats (4 MB), becomes alpha
    float* part = ws + (1u << 20);               // 1M floats (4 MB)
    float* Wh = ws + (2u << 20);                 // 512K floats (2 MB)
    float* s2 = ws + (2u << 20) + (512u << 10);  // 1K floats

    hipLaunchKernelGGL(k1_gemm_wh, dim3(16, 8), dim3(256), 0, stream, H, W, Wh);
    hipLaunchKernelGGL(k1b_s2, dim3(256), dim3(256), 0, stream, Wh, a, s2);
    hipLaunchKernelGGL(k2_scores, dim3(16, 16), dim3(256), 0, stream, Wh, a, s2, scores);
    hipLaunchKernelGGL(k3_softmax, dim3(1024), dim3(256), 0, stream, scores);
    hipLaunchKernelGGL(k4_av, dim3(16, 4, 4), dim3(256), 0, stream, scores, H, part);
    hipLaunchKernelGGL(k5_reduce, dim3(256), dim3(256), 0, stream, part, out);
}

// Round 2
// 68.208 us; speedup vs baseline: 1.4020x; 1.4020x over previous
//
#include <hip/hip_runtime.h>

// GlobalAttention: out = softmax_j(scores) @ H
// scores[i,j] = sum_m lrelu(Wh1[i,m]+Wh2[j,m]) * a[m]
// lrelu(t) = 0.6 t + 0.4|t|; row-constant part drops out of softmax:
// scores'[i,j] = s2[j] + sum_m b[m]*|Wh1[i,m]+Wh2[j,m]|,  b[m]=0.4*a[m],
// s2[j] = 0.6 * sum_m a[m]*Wh2[j,m].
// Pad = 65 (65 == 1 mod 32 -> bank = (row+k) % 32; strided row reads are <=2-way).

#define PAD 65

// ---------- K1: Wh[n][m] = sum_k H[n][k] * Wre[m][k]  (n<1024, m<512, k<256)
// Wre[m][k] = W[m&255][(m>>8)*256 + k].  32x32 tiles -> grid 32x16 = 512 blocks.
__global__ __launch_bounds__(256) void k1_gemm_wh(const float* __restrict__ H,
                                                  const float* __restrict__ W,
                                                  float* __restrict__ Wh) {
    __shared__ float As[32][PAD];
    __shared__ float Bs[32][PAD];
    const int bi = blockIdx.x, bj = blockIdx.y;
    const int t = threadIdx.x;
    const int ti = t >> 4, tj = t & 15;
    const int i0 = ti * 2, j0 = tj * 2;
    const int half = bj >> 3;
    const int lrow = t >> 3, lcol = (t & 7) * 8;
    float acc[2][2] = {};
    for (int kc = 0; kc < 256; kc += 64) {
        *(float4*)&As[lrow][lcol] =
            *(const float4*)&H[(bi * 32 + lrow) * 256 + kc + lcol];
        *(float4*)&As[lrow][lcol + 4] =
            *(const float4*)&H[(bi * 32 + lrow) * 256 + kc + lcol + 4];
        const int wrow = (bj * 32 + lrow) & 255;
        *(float4*)&Bs[lrow][lcol] =
            *(const float4*)&W[wrow * 512 + half * 256 + kc + lcol];
        *(float4*)&Bs[lrow][lcol + 4] =
            *(const float4*)&W[wrow * 512 + half * 256 + kc + lcol + 4];
        __syncthreads();
#pragma unroll
        for (int k = 0; k < 64; k += 4) {
            float4 a[2], b[2];
#pragma unroll
            for (int r = 0; r < 2; ++r) a[r] = *(const float4*)&As[i0 + r][k];
#pragma unroll
            for (int c = 0; c < 2; ++c) b[c] = *(const float4*)&Bs[j0 + c][k];
#pragma unroll
            for (int r = 0; r < 2; ++r)
#pragma unroll
                for (int c = 0; c < 2; ++c) {
                    acc[r][c] = fmaf(a[r].x, b[c].x, acc[r][c]);
                    acc[r][c] = fmaf(a[r].y, b[c].y, acc[r][c]);
                    acc[r][c] = fmaf(a[r].z, b[c].z, acc[r][c]);
                    acc[r][c] = fmaf(a[r].w, b[c].w, acc[r][c]);
                }
        }
        __syncthreads();
    }
#pragma unroll
    for (int r = 0; r < 2; ++r) {
        float2 v = make_float2(acc[r][0], acc[r][1]);
        *(float2*)&Wh[(bi * 32 + i0 + r) * 512 + bj * 32 + j0] = v;
    }
}

// ---------- K1b: s2[j] = 0.6 * sum_m a[m] * Wh2[j][m]   (one wave per row)
__global__ __launch_bounds__(256) void k1b_s2(const float* __restrict__ Wh,
                                              const float* __restrict__ a,
                                              float* __restrict__ s2) {
    const int t = threadIdx.x;
    const int lane = t & 63, w = t >> 6;
    const int row = blockIdx.x * 4 + w;
    float4 x = *(const float4*)&Wh[row * 512 + 256 + lane * 4];
    float4 av = *(const float4*)&a[lane * 4];
    float d = x.x * av.x + x.y * av.y + x.z * av.z + x.w * av.w;
#pragma unroll
    for (int off = 32; off > 0; off >>= 1) d += __shfl_xor(d, off);
    if (lane == 0) s2[row] = 0.6f * d;
}

// ---------- K2: partial[i][j] = sum_{m in half bz} b[m]*|Wh1[i][m]+Wh2[j][m]|
// grid (16,16,2): z splits m into [0,128) -> scores buf, [128,256) -> part buf.
__global__ __launch_bounds__(256) void k2_scores(const float* __restrict__ Wh,
                                                 const float* __restrict__ a,
                                                 float* __restrict__ p0,
                                                 float* __restrict__ p1) {
    __shared__ float X1[64][PAD];
    __shared__ float X2[64][PAD];
    __shared__ float bsh[256];
    const int bi = blockIdx.x, bj = blockIdx.y, bz = blockIdx.z;
    const int t = threadIdx.x;
    const int ti = t >> 4, tj = t & 15;
    const int i0 = ti * 4, j0 = tj * 4;
    if (t < 64) {
        float4 av = *(const float4*)&a[t * 4];
        *(float4*)&bsh[t * 4] =
            make_float4(0.4f * av.x, 0.4f * av.y, 0.4f * av.z, 0.4f * av.w);
    }
    float acc[4][4] = {};
    const int m0 = bz * 128;
    for (int mc = m0; mc < m0 + 128; mc += 64) {
#pragma unroll
        for (int rr = 0; rr < 4; ++rr) {
            const int row = ti + rr * 16;
            const int col = tj * 4;
            *(float4*)&X1[row][col] =
                *(const float4*)&Wh[(bi * 64 + row) * 512 + mc + col];
            *(float4*)&X2[row][col] =
                *(const float4*)&Wh[(bj * 64 + row) * 512 + 256 + mc + col];
        }
        __syncthreads();
#pragma unroll
        for (int k = 0; k < 64; k += 4) {
            float4 x1[4], x2[4];
#pragma unroll
            for (int r = 0; r < 4; ++r) x1[r] = *(const float4*)&X1[i0 + r][k];
#pragma unroll
            for (int c = 0; c < 4; ++c) x2[c] = *(const float4*)&X2[j0 + c][k];
            const float4 bv = *(const float4*)&bsh[mc - m0 + k + (m0 ? 128 : 0)];
#pragma unroll
            for (int r = 0; r < 4; ++r)
#pragma unroll
                for (int c = 0; c < 4; ++c) {
                    acc[r][c] = fmaf(fabsf(x1[r].x + x2[c].x), bv.x, acc[r][c]);
                    acc[r][c] = fmaf(fabsf(x1[r].y + x2[c].y), bv.y, acc[r][c]);
                    acc[r][c] = fmaf(fabsf(x1[r].z + x2[c].z), bv.z, acc[r][c]);
                    acc[r][c] = fmaf(fabsf(x1[r].w + x2[c].w), bv.w, acc[r][c]);
                }
        }
        __syncthreads();
    }
    float* dst = bz ? p1 : p0;
#pragma unroll
    for (int r = 0; r < 4; ++r) {
        float4 v = make_float4(acc[r][0], acc[r][1], acc[r][2], acc[r][3]);
        *(float4*)&dst[(bi * 64 + i0 + r) * 1024 + bj * 64 + j0] = v;
    }
}

// ---------- K3: row softmax of (p0 + p1 + s2[j]), result -> p0 (alpha)
__global__ __launch_bounds__(256) void k3_softmax(float* __restrict__ p0,
                                                  const float* __restrict__ p1,
                                                  const float* __restrict__ s2) {
    const int i = blockIdx.x, t = threadIdx.x;
    __shared__ float red[8];
    float4 va = *(float4*)&p0[i * 1024 + t * 4];
    float4 vb = *(const float4*)&p1[i * 1024 + t * 4];
    float4 vs = *(const float4*)&s2[t * 4];
    float4 v = make_float4(va.x + vb.x + vs.x, va.y + vb.y + vs.y,
                           va.z + vb.z + vs.z, va.w + vb.w + vs.w);
    float m = fmaxf(fmaxf(v.x, v.y), fmaxf(v.z, v.w));
#pragma unroll
    for (int off = 32; off > 0; off >>= 1) m = fmaxf(m, __shfl_xor(m, off));
    const int w = t >> 6;
    if ((t & 63) == 0) red[w] = m;
    __syncthreads();
    const float M = fmaxf(fmaxf(red[0], red[1]), fmaxf(red[2], red[3]));
    float4 e;
    e.x = __expf(v.x - M);
    e.y = __expf(v.y - M);
    e.z = __expf(v.z - M);
    e.w = __expf(v.w - M);
    float s = e.x + e.y + e.z + e.w;
#pragma unroll
    for (int off = 32; off > 0; off >>= 1) s += __shfl_xor(s, off);
    if ((t & 63) == 0) red[4 + w] = s;
    __syncthreads();
    const float rs = 1.0f / (red[4] + red[5] + red[6] + red[7]);
    e.x *= rs; e.y *= rs; e.z *= rs; e.w *= rs;
    *(float4*)&p0[i * 1024 + t * 4] = e;
}

// ---------- K4: part[s][i][c] = sum_{j in split s} alpha[i][j]*H[j][c]
// 64i x 32c tiles, j-split 4 -> grid (16, 8, 4) = 512 blocks.
__global__ __launch_bounds__(256) void k4_av(const float* __restrict__ alpha,
                                             const float* __restrict__ H,
                                             float* __restrict__ part) {
    __shared__ float As[64][PAD];
    __shared__ float Hs[64][33];
    const int bi = blockIdx.x;  // i-tile 0..15
    const int bc = blockIdx.y;  // c-tile 0..7
    const int s = blockIdx.z;   // j-split 0..3
    const int t = threadIdx.x;
    const int ti = t >> 4, tj = t & 15;
    const int i0 = ti * 4, c0 = tj * 2;
    const int hrow = t >> 2, hcol = (t & 3) * 8;
    float acc[4][2] = {};
    for (int jc = s * 256; jc < s * 256 + 256; jc += 64) {
#pragma unroll
        for (int rr = 0; rr < 4; ++rr) {
            const int row = ti + rr * 16;
            const int col = tj * 4;
            *(float4*)&As[row][col] =
                *(const float4*)&alpha[(bi * 64 + row) * 1024 + jc + col];
        }
        *(float4*)&Hs[hrow][hcol] =
            *(const float4*)&H[(jc + hrow) * 256 + bc * 32 + hcol];
        *(float4*)&Hs[hrow][hcol + 4] =
            *(const float4*)&H[(jc + hrow) * 256 + bc * 32 + hcol + 4];
        __syncthreads();
#pragma unroll
        for (int k = 0; k < 64; k += 4) {
            float4 av[4];
            float2 h[4];
#pragma unroll
            for (int r = 0; r < 4; ++r) av[r] = *(const float4*)&As[i0 + r][k];
#pragma unroll
            for (int q = 0; q < 4; ++q) h[q] = *(const float2*)&Hs[k + q][c0];
#pragma unroll
            for (int r = 0; r < 4; ++r) {
                acc[r][0] = fmaf(av[r].x, h[0].x, acc[r][0]);
                acc[r][1] = fmaf(av[r].x, h[0].y, acc[r][1]);
                acc[r][0] = fmaf(av[r].y, h[1].x, acc[r][0]);
                acc[r][1] = fmaf(av[r].y, h[1].y, acc[r][1]);
                acc[r][0] = fmaf(av[r].z, h[2].x, acc[r][0]);
                acc[r][1] = fmaf(av[r].z, h[2].y, acc[r][1]);
                acc[r][0] = fmaf(av[r].w, h[3].x, acc[r][0]);
                acc[r][1] = fmaf(av[r].w, h[3].y, acc[r][1]);
            }
        }
        __syncthreads();
    }
#pragma unroll
    for (int r = 0; r < 4; ++r) {
        float2 v = make_float2(acc[r][0], acc[r][1]);
        *(float2*)&part[s * 262144 + (bi * 64 + i0 + r) * 256 + bc * 32 + c0] = v;
    }
}

// ---------- K5: out = sum of 4 partials
__global__ __launch_bounds__(256) void k5_reduce(const float* __restrict__ part,
                                                 float* __restrict__ out) {
    const int idx = (blockIdx.x * 256 + threadIdx.x) * 4;
    float4 p0 = *(const float4*)&part[idx];
    float4 p1 = *(const float4*)&part[262144 + idx];
    float4 p2 = *(const float4*)&part[524288 + idx];
    float4 p3 = *(const float4*)&part[786432 + idx];
    float4 o = make_float4(p0.x + p1.x + p2.x + p3.x, p0.y + p1.y + p2.y + p3.y,
                           p0.z + p1.z + p2.z + p3.z, p0.w + p1.w + p2.w + p3.w);
    *(float4*)&out[idx] = o;
}

extern "C" void kernel_launch(void* const* d_in, const int* in_sizes, int n_in,
                              void* d_out, int out_size, void* d_ws, size_t ws_size,
                              hipStream_t stream) {
    const float* H = (const float*)d_in[0];
    const float* W = (const float*)d_in[1];
    const float* a = (const float*)d_in[2];
    float* out = (float*)d_out;
    float* ws = (float*)d_ws;

    float* scores = ws;                          // 1M floats: p0, then alpha
    float* part = ws + (1u << 20);               // 1M floats: p1, then AV partials
    float* Wh = ws + (2u << 20);                 // 512K floats
    float* s2 = ws + (2u << 20) + (512u << 10);  // 1K floats

    hipLaunchKernelGGL(k1_gemm_wh, dim3(32, 16), dim3(256), 0, stream, H, W, Wh);
    hipLaunchKernelGGL(k1b_s2, dim3(256), dim3(256), 0, stream, Wh, a, s2);
    hipLaunchKernelGGL(k2_scores, dim3(16, 16, 2), dim3(256), 0, stream, Wh, a, scores, part);
    hipLaunchKernelGGL(k3_softmax, dim3(1024), dim3(256), 0, stream, scores, part, s2);
    hipLaunchKernelGGL(k4_av, dim3(16, 8, 4), dim3(256), 0, stream, scores, H, part);
    hipLaunchKernelGGL(k5_reduce, dim3(256), dim3(256), 0, stream, part, out);
}